// Round 6
// baseline (456.634 us; speedup 1.0000x reference)
//
#include <hip/hip_runtime.h>

// GCN layer: support = X@W ; out = relu(scatter(vals * support[cols]) + bias)
// N_NODES=65536, N_EDGES=1048576, IN_F=OUT_F=64, all fp32 in/out.
//
// R2: counting-sort CSR + per-row gather (replaced 64M fp32 atomics).
// R3: wide 2-kernel scan.  R4: gather x4 unroll; packed int2 edges.
// R5: two-level bucket sort (LDS histograms, block-private staged runs).
// R6: (a) delete CSR: accumulate per-bucket in LDS fp32 (ds_add_f32), write
//     relu(acc+bias) directly -- kills bucket_to_csr + offsets + 16MB traffic.
//     (b) MFMA bf16 GEMM (fp32 path was LDS-bound ~25us), S stored bf16 ->
//     halves random-gather bytes. fp32 accumulation keeps absmax << 0.3.

#define NF     64
#define NBKT   1024          // row buckets; 64 rows each
#define RPB    64            // rows per bucket
#define CHUNK  4096          // edges per scatter-phase block

typedef __attribute__((ext_vector_type(8))) short bf16x8;
typedef __attribute__((ext_vector_type(4))) float floatx4;

__device__ __forceinline__ unsigned short f2bf(float f) {
    unsigned u = __float_as_uint(f);
    return (unsigned short)((u + 0x7FFFu + ((u >> 16) & 1u)) >> 16);   // RNE
}
__device__ __forceinline__ float bf2f(unsigned short h) {
    return __uint_as_float(((unsigned)h) << 16);
}

// ---------------------------------------------------------------------------
// Kernel 1: S16 = bf16(X @ W) via mfma_f32_16x16x32_bf16.
// Block = 256 thr (4 waves), 64 rows/block. X,W converted to bf16 in LDS.
// Rows padded 64->72 bf16 (+16B): lanes r and r+8 alias -> 2-way = free.
// A-frag: A[m=lane&15][k=(lane>>4)*8+j]; B-frag: B[k=(lane>>4)*8+j][n=lane&15];
// C/D: col=lane&15, row=(lane>>4)*4+reg   [guide-verified m89/m91/m120]
// ---------------------------------------------------------------------------
__global__ __launch_bounds__(256) void gemm_bf16(
    const float* __restrict__ X, const float* __restrict__ W,
    unsigned short* __restrict__ S16)
{
    __shared__ short xs[64 * 72];   // X tile,  [row][k]
    __shared__ short wt[64 * 72];   // W^T,     [n][k]

    const int tid  = threadIdx.x;
    const int row0 = blockIdx.x * 64;

    // stage W transposed as bf16
    {
        const float4* W4 = (const float4*)W;
        #pragma unroll
        for (int it = 0; it < 4; ++it) {
            int idx = tid + 256 * it;          // 1024 float4s
            int k = idx >> 4, n4 = idx & 15;
            float4 w = W4[idx];
            wt[(n4 * 4 + 0) * 72 + k] = f2bf(w.x);
            wt[(n4 * 4 + 1) * 72 + k] = f2bf(w.y);
            wt[(n4 * 4 + 2) * 72 + k] = f2bf(w.z);
            wt[(n4 * 4 + 3) * 72 + k] = f2bf(w.w);
        }
    }
    // stage X tile as bf16
    {
        const float4* X4 = (const float4*)X + (size_t)row0 * 16;
        #pragma unroll
        for (int it = 0; it < 4; ++it) {
            int idx = tid + 256 * it;          // 1024 float4s
            int r = idx >> 4, c4 = idx & 15;
            float4 v = X4[idx];
            short4 s = { (short)f2bf(v.x), (short)f2bf(v.y),
                         (short)f2bf(v.z), (short)f2bf(v.w) };
            *(short4*)&xs[r * 72 + c4 * 4] = s;
        }
    }
    __syncthreads();

    const int w    = tid >> 6;          // wave 0..3 -> rows 16w..16w+15
    const int lane = tid & 63;
    const int m    = lane & 15;         // A-row / B-col / D-col
    const int q    = lane >> 4;         // quad

    const int a_off = (16 * w + m) * 72 + q * 8;
    const bf16x8 A0 = *(const bf16x8*)&xs[a_off];
    const bf16x8 A1 = *(const bf16x8*)&xs[a_off + 32];

    floatx4 acc[4];
    #pragma unroll
    for (int t = 0; t < 4; ++t) {
        const int b_off = (16 * t + m) * 72 + q * 8;
        const bf16x8 B0 = *(const bf16x8*)&wt[b_off];
        const bf16x8 B1 = *(const bf16x8*)&wt[b_off + 32];
        floatx4 c = {0.f, 0.f, 0.f, 0.f};
        c = __builtin_amdgcn_mfma_f32_16x16x32_bf16(A0, B0, c, 0, 0, 0);
        c = __builtin_amdgcn_mfma_f32_16x16x32_bf16(A1, B1, c, 0, 0, 0);
        acc[t] = c;
    }

    #pragma unroll
    for (int t = 0; t < 4; ++t)
        #pragma unroll
        for (int r = 0; r < 4; ++r)
            S16[(size_t)(row0 + 16 * w + q * 4 + r) * NF + 16 * t + m] =
                f2bf(acc[t][r]);
}

// ---------------------------------------------------------------------------
// Kernel 2: per-chunk LDS histogram of 1024 row-buckets -> global counts
// ---------------------------------------------------------------------------
__global__ __launch_bounds__(512) void bucket_hist(
    const int* __restrict__ rows, int* __restrict__ bucket_counts,
    int n_edges, int shift)
{
    __shared__ int hist[NBKT];
    const int t = threadIdx.x;
    hist[t] = 0; hist[t + 512] = 0;
    __syncthreads();
    const int base = blockIdx.x * CHUNK;
    const int lim  = min(CHUNK, n_edges - base);
    for (int i = t; i < lim; i += 512)
        atomicAdd(&hist[((unsigned)rows[base + i]) >> shift], 1);
    __syncthreads();
    #pragma unroll
    for (int b = t; b < NBKT; b += 512)
        if (hist[b]) atomicAdd(&bucket_counts[b], hist[b]);
}

// ---------------------------------------------------------------------------
// Kernel 3: scan 1024 bucket counts -> bucketbase + cursor (single block)
// ---------------------------------------------------------------------------
__global__ __launch_bounds__(512) void scan_buckets(
    const int* __restrict__ bucket_counts, int* __restrict__ bucketbase,
    int* __restrict__ bucket_cursor, int n_edges)
{
    __shared__ int sh[512];
    const int t = threadIdx.x;
    const int v0 = bucket_counts[2 * t];
    const int v1 = bucket_counts[2 * t + 1];
    sh[t] = v0 + v1;
    __syncthreads();
    for (int off = 1; off < 512; off <<= 1) {
        int u = (t >= off) ? sh[t - off] : 0;
        __syncthreads();
        sh[t] += u;
        __syncthreads();
    }
    const int base = (t == 0) ? 0 : sh[t - 1];
    bucketbase[2 * t]       = base;
    bucketbase[2 * t + 1]   = base + v0;
    bucket_cursor[2 * t]     = base;
    bucket_cursor[2 * t + 1] = base + v0;
    if (t == 511) bucketbase[NBKT] = n_edges;
}

// ---------------------------------------------------------------------------
// Kernel 4: bin each 4096-edge chunk into bucket runs. LDS cursors; one
// global atomic per (block,bucket); packed (row<<16|col, val) 8B edges.
// ---------------------------------------------------------------------------
__global__ __launch_bounds__(512) void bucket_scatter(
    const int* __restrict__ rows, const int* __restrict__ cols,
    const float* __restrict__ vals, int* __restrict__ bucket_cursor,
    int2* __restrict__ staged, int n_edges, int shift)
{
    __shared__ int hist[NBKT];
    __shared__ int cur[NBKT];
    const int t = threadIdx.x;
    hist[t] = 0; hist[t + 512] = 0;
    __syncthreads();
    const int base = blockIdx.x * CHUNK;
    const int lim  = min(CHUNK, n_edges - base);
    for (int i = t; i < lim; i += 512)
        atomicAdd(&hist[((unsigned)rows[base + i]) >> shift], 1);
    __syncthreads();
    #pragma unroll
    for (int b = t; b < NBKT; b += 512)
        cur[b] = hist[b] ? atomicAdd(&bucket_cursor[b], hist[b]) : 0;
    __syncthreads();
    for (int i = t; i < lim; i += 512) {
        int r = rows[base + i];
        int b = ((unsigned)r) >> shift;
        int p = atomicAdd(&cur[b], 1);
        staged[p] = make_int2((int)(((unsigned)r << 16) | (unsigned)cols[base + i]),
                              __float_as_int(vals[base + i]));
    }
}

// ---------------------------------------------------------------------------
// Kernel 5: one block per bucket. Zero 64x64 fp32 LDS accumulator; each wave
// walks a quarter of the bucket's staged edges (whole wave per edge,
// lane = feature): acc[lrow][lane] += val * S16[col][lane] via ds_add_f32.
// Epilogue: out = relu(acc + bias), coalesced float4.
// ---------------------------------------------------------------------------
__global__ __launch_bounds__(256) void bucket_accum(
    const int* __restrict__ bucketbase, const int2* __restrict__ staged,
    const unsigned short* __restrict__ S16, const float* __restrict__ bias,
    float* __restrict__ out)
{
    __shared__ float acc[RPB * NF];     // 16 KB
    const int k    = blockIdx.x;
    const int tid  = threadIdx.x;
    const int w    = tid >> 6;
    const int lane = tid & 63;

    #pragma unroll
    for (int i = tid; i < RPB * NF; i += 256) acc[i] = 0.f;
    __syncthreads();

    const int beg = bucketbase[k];
    const int end = bucketbase[k + 1];
    const int cnt = end - beg;
    const int per = (cnt + 3) >> 2;
    int j    = beg + w * per;
    int wend = min(j + per, end);

    for (; j + 4 <= wend; j += 4) {
        const int2 e0 = staged[j + 0];
        const int2 e1 = staged[j + 1];
        const int2 e2 = staged[j + 2];
        const int2 e3 = staged[j + 3];
        const float s0 = bf2f(S16[(size_t)(e0.x & 0xFFFF) * NF + lane]);
        const float s1 = bf2f(S16[(size_t)(e1.x & 0xFFFF) * NF + lane]);
        const float s2 = bf2f(S16[(size_t)(e2.x & 0xFFFF) * NF + lane]);
        const float s3 = bf2f(S16[(size_t)(e3.x & 0xFFFF) * NF + lane]);
        atomicAdd(&acc[((((unsigned)e0.x) >> 16) & (RPB - 1)) * NF + lane],
                  __int_as_float(e0.y) * s0);
        atomicAdd(&acc[((((unsigned)e1.x) >> 16) & (RPB - 1)) * NF + lane],
                  __int_as_float(e1.y) * s1);
        atomicAdd(&acc[((((unsigned)e2.x) >> 16) & (RPB - 1)) * NF + lane],
                  __int_as_float(e2.y) * s2);
        atomicAdd(&acc[((((unsigned)e3.x) >> 16) & (RPB - 1)) * NF + lane],
                  __int_as_float(e3.y) * s3);
    }
    for (; j < wend; ++j) {
        const int2 e = staged[j];
        const float s = bf2f(S16[(size_t)(e.x & 0xFFFF) * NF + lane]);
        atomicAdd(&acc[((((unsigned)e.x) >> 16) & (RPB - 1)) * NF + lane],
                  __int_as_float(e.y) * s);
    }
    __syncthreads();

    // epilogue: relu(acc + bias) -> out, 16 floats (4 float4) per thread
    const float4* bias4 = (const float4*)bias;
    float4* out4 = (float4*)(out + (size_t)k * RPB * NF);
    #pragma unroll
    for (int p = 0; p < 4; ++p) {
        int idx = tid + 256 * p;            // float4 index within bucket tile
        int c4  = idx & 15;
        float4 a = *(float4*)&acc[idx * 4];
        float4 b = bias4[c4];
        float4 o;
        o.x = fmaxf(a.x + b.x, 0.f); o.y = fmaxf(a.y + b.y, 0.f);
        o.z = fmaxf(a.z + b.z, 0.f); o.w = fmaxf(a.w + b.w, 0.f);
        out4[idx] = o;
    }
}

extern "C" void kernel_launch(void* const* d_in, const int* in_sizes, int n_in,
                              void* d_out, int out_size, void* d_ws, size_t ws_size,
                              hipStream_t stream)
{
    const float* X     = (const float*)d_in[0];
    const int*   erows = (const int*)  d_in[1];
    const int*   ecols = (const int*)  d_in[2];
    const float* evals = (const float*)d_in[3];
    const float* W     = (const float*)d_in[4];
    const float* bias  = (const float*)d_in[5];
    float*       out   = (float*)d_out;

    const int n_nodes = in_sizes[0] / NF;
    const int n_edges = in_sizes[1];
    int shift = 0; while ((NBKT << shift) < n_nodes) ++shift;   // 6

    // workspace layout
    char* ws = (char*)d_ws;
    unsigned short* S16        = (unsigned short*)(ws);                       // 8 MB
    int2*           staged     = (int2*)(ws + (size_t)n_nodes * NF * 2);      // 8 MB
    int*            bucket_counts = (int*)((char*)staged + (size_t)n_edges * 8);
    int*            bucketbase    = (int*)((char*)bucket_counts + (NBKT + 16) * 4);
    int*            bucket_cursor = (int*)((char*)bucketbase    + (NBKT + 16) * 4);

    const int ablocks = (n_edges + CHUNK - 1) / CHUNK;   // 256

    gemm_bf16    <<<n_nodes / 64, 256, 0, stream>>>(X, W, S16);
    hipMemsetAsync(bucket_counts, 0, (size_t)NBKT * 4, stream);
    bucket_hist  <<<ablocks, 512, 0, stream>>>(erows, bucket_counts, n_edges, shift);
    scan_buckets <<<1, 512, 0, stream>>>(bucket_counts, bucketbase, bucket_cursor,
                                         n_edges);
    bucket_scatter<<<ablocks, 512, 0, stream>>>(erows, ecols, evals, bucket_cursor,
                                                staged, n_edges, shift);
    bucket_accum <<<NBKT, 256, 0, stream>>>(bucketbase, staged, S16, bias, out);
}

// Round 7
// 151.966 us; speedup vs baseline: 3.0049x; 3.0049x over previous
//
#include <hip/hip_runtime.h>

// GCN layer: support = X@W ; out = relu(csr_gather(vals * support[cols]) + bias)
// N_NODES=65536, N_EDGES=1048576, IN_F=OUT_F=64, fp32 in/out.
//
// R2: counting-sort CSR + per-row gather (replaced 64M fp32 atomics).
// R3: wide scan.  R4: gather x4 unroll; packed int2 edges.
// R5: two-level bucket sort CSR build (169us total).
// R6: FAILED -- LDS-accum engine had 4096 waves vs gather's 65536; the
//     latency-bound edge->S chain needs wave-count, not traffic reduction.
// R7: R5 pipeline + R6's two verified-good parts: MFMA bf16 GEMM (~25->~10us)
//     and bf16 S (halves gather's random S bytes); gather unroll 4->8.

#define NF    64
#define NBKT  512      // row buckets; 128 rows each (shift=7)
#define CHUNK 4096     // edges per phase-A block

typedef __attribute__((ext_vector_type(8))) short bf16x8;
typedef __attribute__((ext_vector_type(4))) float floatx4;

__device__ __forceinline__ unsigned short f2bf(float f) {
    unsigned u = __float_as_uint(f);
    return (unsigned short)((u + 0x7FFFu + ((u >> 16) & 1u)) >> 16);   // RNE
}
__device__ __forceinline__ float bf2f(unsigned short h) {
    return __uint_as_float(((unsigned)h) << 16);
}

// ---------------------------------------------------------------------------
// Kernel 1: S16 = bf16(X @ W) via mfma_f32_16x16x32_bf16.
// Block = 256 thr (4 waves), 64 rows/block. X,W -> bf16 in LDS (rows padded
// 64->72: 2-way bank alias = free). Layouts guide-verified (m89/m91).
// ---------------------------------------------------------------------------
__global__ __launch_bounds__(256) void gemm_bf16(
    const float* __restrict__ X, const float* __restrict__ W,
    unsigned short* __restrict__ S16)
{
    __shared__ short xs[64 * 72];   // X tile,  [row][k]
    __shared__ short wt[64 * 72];   // W^T,     [n][k]

    const int tid  = threadIdx.x;
    const int row0 = blockIdx.x * 64;

    {
        const float4* W4 = (const float4*)W;
        #pragma unroll
        for (int it = 0; it < 4; ++it) {
            int idx = tid + 256 * it;          // 1024 float4s
            int k = idx >> 4, n4 = idx & 15;
            float4 w = W4[idx];
            wt[(n4 * 4 + 0) * 72 + k] = f2bf(w.x);
            wt[(n4 * 4 + 1) * 72 + k] = f2bf(w.y);
            wt[(n4 * 4 + 2) * 72 + k] = f2bf(w.z);
            wt[(n4 * 4 + 3) * 72 + k] = f2bf(w.w);
        }
    }
    {
        const float4* X4 = (const float4*)X + (size_t)row0 * 16;
        #pragma unroll
        for (int it = 0; it < 4; ++it) {
            int idx = tid + 256 * it;          // 1024 float4s
            int r = idx >> 4, c4 = idx & 15;
            float4 v = X4[idx];
            short4 s = { (short)f2bf(v.x), (short)f2bf(v.y),
                         (short)f2bf(v.z), (short)f2bf(v.w) };
            *(short4*)&xs[r * 72 + c4 * 4] = s;
        }
    }
    __syncthreads();

    const int w    = tid >> 6;
    const int lane = tid & 63;
    const int m    = lane & 15;
    const int q    = lane >> 4;

    const int a_off = (16 * w + m) * 72 + q * 8;
    const bf16x8 A0 = *(const bf16x8*)&xs[a_off];
    const bf16x8 A1 = *(const bf16x8*)&xs[a_off + 32];

    floatx4 acc[4];
    #pragma unroll
    for (int t = 0; t < 4; ++t) {
        const int b_off = (16 * t + m) * 72 + q * 8;
        const bf16x8 B0 = *(const bf16x8*)&wt[b_off];
        const bf16x8 B1 = *(const bf16x8*)&wt[b_off + 32];
        floatx4 c = {0.f, 0.f, 0.f, 0.f};
        c = __builtin_amdgcn_mfma_f32_16x16x32_bf16(A0, B0, c, 0, 0, 0);
        c = __builtin_amdgcn_mfma_f32_16x16x32_bf16(A1, B1, c, 0, 0, 0);
        acc[t] = c;
    }

    #pragma unroll
    for (int t = 0; t < 4; ++t)
        #pragma unroll
        for (int r = 0; r < 4; ++r)
            S16[(size_t)(row0 + 16 * w + q * 4 + r) * NF + 16 * t + m] =
                f2bf(acc[t][r]);
}

// ---------------------------------------------------------------------------
// Kernel 2: per-chunk LDS histogram of 512 row-buckets -> global bucket counts
// ---------------------------------------------------------------------------
__global__ __launch_bounds__(512) void bucket_hist(
    const int* __restrict__ rows, int* __restrict__ bucket_counts,
    int n_edges, int shift)
{
    __shared__ int hist[NBKT];
    const int t = threadIdx.x;
    hist[t] = 0;
    __syncthreads();
    const int base = blockIdx.x * CHUNK;
    const int lim  = min(CHUNK, n_edges - base);
    for (int i = t; i < lim; i += 512)
        atomicAdd(&hist[((unsigned)rows[base + i]) >> shift], 1);
    __syncthreads();
    if (hist[t]) atomicAdd(&bucket_counts[t], hist[t]);
}

// ---------------------------------------------------------------------------
// Kernel 3: scan 512 bucket counts -> bucketbase + cursor init (single block)
// ---------------------------------------------------------------------------
__global__ __launch_bounds__(512) void scan_buckets(
    const int* __restrict__ bucket_counts, int* __restrict__ bucketbase,
    int* __restrict__ bucket_cursor, int* __restrict__ offsets,
    int n_edges, int n_nodes)
{
    __shared__ int sh[NBKT];
    const int t = threadIdx.x;
    const int v = bucket_counts[t];
    sh[t] = v;
    __syncthreads();
    for (int off = 1; off < NBKT; off <<= 1) {
        int u = (t >= off) ? sh[t - off] : 0;
        __syncthreads();
        sh[t] += u;
        __syncthreads();
    }
    const int excl = sh[t] - v;
    bucketbase[t]    = excl;
    bucket_cursor[t] = excl;
    if (t == NBKT - 1) { bucketbase[NBKT] = n_edges; offsets[n_nodes] = n_edges; }
}

// ---------------------------------------------------------------------------
// Kernel 4: bin each chunk into bucket runs. LDS cursors; ONE global atomic
// per (block,bucket) reservation; packed 8B edges into block-private runs.
// ---------------------------------------------------------------------------
__global__ __launch_bounds__(512) void bucket_scatter(
    const int* __restrict__ rows, const int* __restrict__ cols,
    const float* __restrict__ vals, int* __restrict__ bucket_cursor,
    int2* __restrict__ staged, int n_edges, int shift)
{
    __shared__ int hist[NBKT];
    __shared__ int cur[NBKT];
    __shared__ int lrow[CHUNK];
    const int t = threadIdx.x;
    hist[t] = 0;
    __syncthreads();
    const int base = blockIdx.x * CHUNK;
    const int lim  = min(CHUNK, n_edges - base);
    for (int i = t; i < lim; i += 512) {
        int r = rows[base + i];
        lrow[i] = r;
        atomicAdd(&hist[((unsigned)r) >> shift], 1);
    }
    __syncthreads();
    cur[t] = hist[t] ? atomicAdd(&bucket_cursor[t], hist[t]) : 0;
    __syncthreads();
    for (int i = t; i < lim; i += 512) {
        int r = lrow[i];
        int b = ((unsigned)r) >> shift;
        int p = atomicAdd(&cur[b], 1);
        staged[p] = make_int2((int)(((unsigned)r << 16) | (unsigned)cols[base + i]),
                              __float_as_int(vals[base + i]));
    }
}

// ---------------------------------------------------------------------------
// Kernel 5: one block per bucket: LDS row-histogram -> LDS scan -> write
// offsets[] -> LDS-cursor scatter into the bucket's contiguous spack region.
// ---------------------------------------------------------------------------
__global__ __launch_bounds__(256) void bucket_to_csr(
    const int* __restrict__ bucketbase, const int2* __restrict__ staged,
    int* __restrict__ offsets, int2* __restrict__ spack, int rows_per_bkt)
{
    __shared__ int hist[128];
    __shared__ int cur[128];
    const int k = blockIdx.x;
    const int t = threadIdx.x;
    const int base = bucketbase[k];
    const int end  = bucketbase[k + 1];
    const int mask = rows_per_bkt - 1;

    if (t < rows_per_bkt) hist[t] = 0;
    __syncthreads();
    for (int i = base + t; i < end; i += 256)
        atomicAdd(&hist[(((unsigned)staged[i].x) >> 16) & mask], 1);
    __syncthreads();

    const int v = (t < rows_per_bkt) ? hist[t] : 0;
    for (int off = 1; off < 128; off <<= 1) {
        int u = (t < rows_per_bkt && t >= off) ? hist[t - off] : 0;
        __syncthreads();
        if (t < rows_per_bkt) hist[t] += u;
        __syncthreads();
    }
    if (t < rows_per_bkt) {
        const int pos = base + hist[t] - v;     // exclusive
        offsets[k * rows_per_bkt + t] = pos;
        cur[t] = pos;
    }
    __syncthreads();
    for (int i = base + t; i < end; i += 256) {
        int2 e = staged[i];
        int r = (((unsigned)e.x) >> 16) & mask;
        int p = atomicAdd(&cur[r], 1);
        spack[p] = make_int2(e.x & 0xFFFF, e.y);
    }
}

// ---------------------------------------------------------------------------
// Kernel 6: per-row gather-accumulate from bf16 S, fused bias + ReLU.
// One 64-lane wave per destination row; unrolled x8 for MLP.
// ---------------------------------------------------------------------------
__global__ __launch_bounds__(256) void gather_rows(
    const int* __restrict__ offsets, const int2* __restrict__ spack,
    const unsigned short* __restrict__ S16, const float* __restrict__ bias,
    float* __restrict__ out, int n_rows)
{
    const int row  = (blockIdx.x * 256 + threadIdx.x) >> 6;
    const int lane = threadIdx.x & 63;
    if (row >= n_rows) return;

    const int beg = __builtin_amdgcn_readfirstlane(offsets[row]);
    const int end = __builtin_amdgcn_readfirstlane(offsets[row + 1]);

    float a0 = 0.f, a1 = 0.f, a2 = 0.f, a3 = 0.f;
    float a4 = 0.f, a5 = 0.f, a6 = 0.f, a7 = 0.f;
    int j = beg;
    for (; j + 8 <= end; j += 8) {
        const int2 e0 = spack[j + 0];
        const int2 e1 = spack[j + 1];
        const int2 e2 = spack[j + 2];
        const int2 e3 = spack[j + 3];
        const int2 e4 = spack[j + 4];
        const int2 e5 = spack[j + 5];
        const int2 e6 = spack[j + 6];
        const int2 e7 = spack[j + 7];
        a0 += __int_as_float(e0.y) * bf2f(S16[(size_t)e0.x * NF + lane]);
        a1 += __int_as_float(e1.y) * bf2f(S16[(size_t)e1.x * NF + lane]);
        a2 += __int_as_float(e2.y) * bf2f(S16[(size_t)e2.x * NF + lane]);
        a3 += __int_as_float(e3.y) * bf2f(S16[(size_t)e3.x * NF + lane]);
        a4 += __int_as_float(e4.y) * bf2f(S16[(size_t)e4.x * NF + lane]);
        a5 += __int_as_float(e5.y) * bf2f(S16[(size_t)e5.x * NF + lane]);
        a6 += __int_as_float(e6.y) * bf2f(S16[(size_t)e6.x * NF + lane]);
        a7 += __int_as_float(e7.y) * bf2f(S16[(size_t)e7.x * NF + lane]);
    }
    for (; j + 2 <= end; j += 2) {
        const int2 e0 = spack[j + 0];
        const int2 e1 = spack[j + 1];
        a0 += __int_as_float(e0.y) * bf2f(S16[(size_t)e0.x * NF + lane]);
        a1 += __int_as_float(e1.y) * bf2f(S16[(size_t)e1.x * NF + lane]);
    }
    if (j < end) {
        const int2 e = spack[j];
        a0 += __int_as_float(e.y) * bf2f(S16[(size_t)e.x * NF + lane]);
    }
    const float acc = bias[lane] +
        (((a0 + a1) + (a2 + a3)) + ((a4 + a5) + (a6 + a7)));
    out[(size_t)row * NF + lane] = fmaxf(acc, 0.f);
}

extern "C" void kernel_launch(void* const* d_in, const int* in_sizes, int n_in,
                              void* d_out, int out_size, void* d_ws, size_t ws_size,
                              hipStream_t stream)
{
    const float* X     = (const float*)d_in[0];
    const int*   erows = (const int*)  d_in[1];
    const int*   ecols = (const int*)  d_in[2];
    const float* evals = (const float*)d_in[3];
    const float* W     = (const float*)d_in[4];
    const float* bias  = (const float*)d_in[5];
    float*       out   = (float*)d_out;

    const int n_nodes = in_sizes[0] / NF;
    const int n_edges = in_sizes[1];
    const int rows_per_bkt = n_nodes / NBKT;        // 128
    int shift = 0; while ((NBKT << shift) < n_nodes) ++shift;   // 7

    // workspace layout
    char* ws = (char*)d_ws;
    unsigned short* S16 = (unsigned short*)(ws);                           // 8 MB
    int2*  staged        = (int2*) (ws + (size_t)n_nodes * NF * 2);        // 8 MB
    int2*  spack         = (int2*) ((char*)staged + (size_t)n_edges * 8);  // 8 MB
    int*   offsets       = (int*)  ((char*)spack  + (size_t)n_edges * 8);  // 256 KB
    int*   bucket_counts = (int*)  ((char*)offsets + (size_t)(n_nodes + 4) * 4);
    int*   bucketbase    = (int*)  ((char*)bucket_counts + (NBKT + 4) * 4);
    int*   bucket_cursor = (int*)  ((char*)bucketbase   + (NBKT + 4) * 4);

    const int ablocks = (n_edges + CHUNK - 1) / CHUNK;   // 256

    gemm_bf16    <<<n_nodes / 64, 256, 0, stream>>>(X, W, S16);
    hipMemsetAsync(bucket_counts, 0, (size_t)NBKT * 4, stream);
    bucket_hist  <<<ablocks, 512, 0, stream>>>(erows, bucket_counts, n_edges, shift);
    scan_buckets <<<1, NBKT, 0, stream>>>(bucket_counts, bucketbase, bucket_cursor,
                                          offsets, n_edges, n_nodes);
    bucket_scatter<<<ablocks, 512, 0, stream>>>(erows, ecols, evals, bucket_cursor,
                                                staged, n_edges, shift);
    bucket_to_csr<<<NBKT, 256, 0, stream>>>(bucketbase, staged, offsets, spack,
                                            rows_per_bkt);
    gather_rows  <<<(n_nodes * 64 + 255) / 256, 256, 0, stream>>>(
        offsets, spack, S16, bias, out, n_nodes);
}

// Round 8
// 143.897 us; speedup vs baseline: 3.1733x; 1.0561x over previous
//
#include <hip/hip_runtime.h>

// GCN layer: support = X@W ; out = relu(scatter(vals * support[cols]) + bias)
// N_NODES=65536, N_EDGES=1048576, IN_F=OUT_F=64, fp32 in/out.
//
// R2: counting-sort CSR + per-row gather (replaced 64M fp32 atomics).
// R5: two-level bucket sort CSR build. R6 FAILED: 4096-wave LDS-accum engine
//     (latency-bound edge->S chain needs wave count). R7: MFMA bf16 GEMM +
//     bf16 S (152us).
// R8: (a) fuse CSR-build + gather: sort bucket edges into LDS, 16 waves x 8
//     wave-exclusive rows gather with register accumulators (8192 waves) --
//     deletes spack 8MB write + 8MB read + offsets + 1 launch.
//     (b) fuse bucket histogram into the GEMM (hides under MFMA, -1 launch).
//     (c) bucket_scatter keeps its 8 edges/thread in VGPRs (int4 loads, no
//     lrow LDS).

#define NF    64
#define NBKT  512      // row buckets; 128 rows each (shift=7)
#define RPB   128      // rows per bucket
#define CHUNK 4096     // edges per scatter block
#define CAP   4096     // max edges sorted in LDS per bucket (mean 2048, 45-sigma)

typedef __attribute__((ext_vector_type(8))) short bf16x8;
typedef __attribute__((ext_vector_type(4))) float floatx4;

__device__ __forceinline__ unsigned short f2bf(float f) {
    unsigned u = __float_as_uint(f);
    return (unsigned short)((u + 0x7FFFu + ((u >> 16) & 1u)) >> 16);   // RNE
}
__device__ __forceinline__ float bf2f(unsigned short h) {
    return __uint_as_float(((unsigned)h) << 16);
}

// ---------------------------------------------------------------------------
// Kernel 1: S16 = bf16(X @ W) via mfma_f32_16x16x32_bf16, with the 512-bucket
// edge histogram fused in (each of the 1024 blocks hists a 1024-edge chunk;
// the edge loads hide under MFMA). Layouts guide-verified (m89/m91).
// ---------------------------------------------------------------------------
__global__ __launch_bounds__(256) void gemm_bf16_hist(
    const float* __restrict__ X, const float* __restrict__ W,
    unsigned short* __restrict__ S16,
    const int* __restrict__ erows, int* __restrict__ bucket_counts,
    int n_edges, int shift)
{
    __shared__ short xs[64 * 72];   // X tile,  [row][k] (pad: 2-way alias, free)
    __shared__ short wt[64 * 72];   // W^T,     [n][k]
    __shared__ int   hist[NBKT];    // 2 KB

    const int tid  = threadIdx.x;
    const int row0 = blockIdx.x * 64;

    for (int i = tid; i < NBKT; i += 256) hist[i] = 0;
    {
        const float4* W4 = (const float4*)W;
        #pragma unroll
        for (int it = 0; it < 4; ++it) {
            int idx = tid + 256 * it;          // 1024 float4s
            int k = idx >> 4, n4 = idx & 15;
            float4 w = W4[idx];
            wt[(n4 * 4 + 0) * 72 + k] = f2bf(w.x);
            wt[(n4 * 4 + 1) * 72 + k] = f2bf(w.y);
            wt[(n4 * 4 + 2) * 72 + k] = f2bf(w.z);
            wt[(n4 * 4 + 3) * 72 + k] = f2bf(w.w);
        }
    }
    {
        const float4* X4 = (const float4*)X + (size_t)row0 * 16;
        #pragma unroll
        for (int it = 0; it < 4; ++it) {
            int idx = tid + 256 * it;          // 1024 float4s
            int r = idx >> 4, c4 = idx & 15;
            float4 v = X4[idx];
            short4 s = { (short)f2bf(v.x), (short)f2bf(v.y),
                         (short)f2bf(v.z), (short)f2bf(v.w) };
            *(short4*)&xs[r * 72 + c4 * 4] = s;
        }
    }
    __syncthreads();

    const int w    = tid >> 6;
    const int lane = tid & 63;
    const int m    = lane & 15;
    const int q    = lane >> 4;

    const int a_off = (16 * w + m) * 72 + q * 8;
    const bf16x8 A0 = *(const bf16x8*)&xs[a_off];
    const bf16x8 A1 = *(const bf16x8*)&xs[a_off + 32];

    floatx4 acc[4];
    #pragma unroll
    for (int t = 0; t < 4; ++t) {
        const int b_off = (16 * t + m) * 72 + q * 8;
        const bf16x8 B0 = *(const bf16x8*)&wt[b_off];
        const bf16x8 B1 = *(const bf16x8*)&wt[b_off + 32];
        floatx4 c = {0.f, 0.f, 0.f, 0.f};
        c = __builtin_amdgcn_mfma_f32_16x16x32_bf16(A0, B0, c, 0, 0, 0);
        c = __builtin_amdgcn_mfma_f32_16x16x32_bf16(A1, B1, c, 0, 0, 0);
        acc[t] = c;
    }

    #pragma unroll
    for (int t = 0; t < 4; ++t)
        #pragma unroll
        for (int r = 0; r < 4; ++r)
            S16[(size_t)(row0 + 16 * w + q * 4 + r) * NF + 16 * t + m] =
                f2bf(acc[t][r]);

    // fused histogram: this block's 1024-edge chunk (4 edges/thread, int4)
    {
        const int ebase = blockIdx.x * 1024;
        if (ebase < n_edges) {
            const int lim = min(1024, n_edges - ebase);
            if (lim == 1024) {
                int4 r4 = ((const int4*)(erows + ebase))[tid];
                atomicAdd(&hist[((unsigned)r4.x) >> shift], 1);
                atomicAdd(&hist[((unsigned)r4.y) >> shift], 1);
                atomicAdd(&hist[((unsigned)r4.z) >> shift], 1);
                atomicAdd(&hist[((unsigned)r4.w) >> shift], 1);
            } else {
                for (int i = tid; i < lim; i += 256)
                    atomicAdd(&hist[((unsigned)erows[ebase + i]) >> shift], 1);
            }
        }
        __syncthreads();
        for (int b = tid; b < NBKT; b += 256)
            if (hist[b]) atomicAdd(&bucket_counts[b], hist[b]);
    }
}

// ---------------------------------------------------------------------------
// Kernel 2: scan 512 bucket counts -> bucketbase + cursor init (single block)
// ---------------------------------------------------------------------------
__global__ __launch_bounds__(512) void scan_buckets(
    const int* __restrict__ bucket_counts, int* __restrict__ bucketbase,
    int* __restrict__ bucket_cursor, int n_edges)
{
    __shared__ int sh[NBKT];
    const int t = threadIdx.x;
    const int v = bucket_counts[t];
    sh[t] = v;
    __syncthreads();
    for (int off = 1; off < NBKT; off <<= 1) {
        int u = (t >= off) ? sh[t - off] : 0;
        __syncthreads();
        sh[t] += u;
        __syncthreads();
    }
    const int excl = sh[t] - v;
    bucketbase[t]    = excl;
    bucket_cursor[t] = excl;
    if (t == NBKT - 1) bucketbase[NBKT] = n_edges;
}

// ---------------------------------------------------------------------------
// Kernel 3: bin each 4096-edge chunk into bucket runs. 8 edges/thread held in
// VGPRs across the syncs (no lrow LDS); one global atomic per (block,bucket).
// ---------------------------------------------------------------------------
__global__ __launch_bounds__(512) void bucket_scatter(
    const int* __restrict__ rows, const int* __restrict__ cols,
    const float* __restrict__ vals, int* __restrict__ bucket_cursor,
    int2* __restrict__ staged, int n_edges, int shift)
{
    __shared__ int hist[NBKT];
    __shared__ int cur[NBKT];
    const int t = threadIdx.x;
    hist[t] = 0;
    __syncthreads();
    const int base = blockIdx.x * CHUNK;
    const int lim  = min(CHUNK, n_edges - base);

    if (lim == CHUNK) {
        const int4*   R4 = (const int4*)(rows + base);
        const int4*   C4 = (const int4*)(cols + base);
        const float4* V4 = (const float4*)(vals + base);
        int4 r0 = R4[t], r1 = R4[t + 512];
        atomicAdd(&hist[((unsigned)r0.x) >> shift], 1);
        atomicAdd(&hist[((unsigned)r0.y) >> shift], 1);
        atomicAdd(&hist[((unsigned)r0.z) >> shift], 1);
        atomicAdd(&hist[((unsigned)r0.w) >> shift], 1);
        atomicAdd(&hist[((unsigned)r1.x) >> shift], 1);
        atomicAdd(&hist[((unsigned)r1.y) >> shift], 1);
        atomicAdd(&hist[((unsigned)r1.z) >> shift], 1);
        atomicAdd(&hist[((unsigned)r1.w) >> shift], 1);
        __syncthreads();
        cur[t] = hist[t] ? atomicAdd(&bucket_cursor[t], hist[t]) : 0;
        __syncthreads();
        int4 c0 = C4[t], c1 = C4[t + 512];
        float4 v0 = V4[t], v1 = V4[t + 512];
        int p;
        p = atomicAdd(&cur[((unsigned)r0.x) >> shift], 1);
        staged[p] = make_int2((int)(((unsigned)r0.x << 16) | (unsigned)c0.x), __float_as_int(v0.x));
        p = atomicAdd(&cur[((unsigned)r0.y) >> shift], 1);
        staged[p] = make_int2((int)(((unsigned)r0.y << 16) | (unsigned)c0.y), __float_as_int(v0.y));
        p = atomicAdd(&cur[((unsigned)r0.z) >> shift], 1);
        staged[p] = make_int2((int)(((unsigned)r0.z << 16) | (unsigned)c0.z), __float_as_int(v0.z));
        p = atomicAdd(&cur[((unsigned)r0.w) >> shift], 1);
        staged[p] = make_int2((int)(((unsigned)r0.w << 16) | (unsigned)c0.w), __float_as_int(v0.w));
        p = atomicAdd(&cur[((unsigned)r1.x) >> shift], 1);
        staged[p] = make_int2((int)(((unsigned)r1.x << 16) | (unsigned)c1.x), __float_as_int(v1.x));
        p = atomicAdd(&cur[((unsigned)r1.y) >> shift], 1);
        staged[p] = make_int2((int)(((unsigned)r1.y << 16) | (unsigned)c1.y), __float_as_int(v1.y));
        p = atomicAdd(&cur[((unsigned)r1.z) >> shift], 1);
        staged[p] = make_int2((int)(((unsigned)r1.z << 16) | (unsigned)c1.z), __float_as_int(v1.z));
        p = atomicAdd(&cur[((unsigned)r1.w) >> shift], 1);
        staged[p] = make_int2((int)(((unsigned)r1.w << 16) | (unsigned)c1.w), __float_as_int(v1.w));
    } else {
        for (int i = t; i < lim; i += 512)
            atomicAdd(&hist[((unsigned)rows[base + i]) >> shift], 1);
        __syncthreads();
        cur[t] = hist[t] ? atomicAdd(&bucket_cursor[t], hist[t]) : 0;
        __syncthreads();
        for (int i = t; i < lim; i += 512) {
            int r = rows[base + i];
            int p = atomicAdd(&cur[((unsigned)r) >> shift], 1);
            staged[p] = make_int2((int)(((unsigned)r << 16) | (unsigned)cols[base + i]),
                                  __float_as_int(vals[base + i]));
        }
    }
}

// ---------------------------------------------------------------------------
// Kernel 4: one block (1024 thr, 16 waves) per bucket. Phase A: sort the
// bucket's edges into LDS (row-hist -> scan -> LDS-cursor scatter).
// Phase B: wave w owns rows 8w..8w+7 exclusively; register accumulate with
// x8-unrolled random S16 loads; fused bias+ReLU store. 8192 waves total.
// Fallback (cnt > CAP, never on this data): R6-style LDS fp32 accumulate.
// ---------------------------------------------------------------------------
__global__ __launch_bounds__(1024) void bucket_gather(
    const int* __restrict__ bucketbase, const int2* __restrict__ staged,
    const unsigned short* __restrict__ S16, const float* __restrict__ bias,
    float* __restrict__ out)
{
    __shared__ int2 eds[CAP];          // 32 KB (fallback reuses as float[8192])
    __shared__ int  hist[RPB];
    __shared__ int  cur[RPB];
    __shared__ int  rstart[RPB + 1];

    const int k   = blockIdx.x;
    const int t   = threadIdx.x;
    const int base = bucketbase[k];
    const int end  = bucketbase[k + 1];
    const int cnt  = end - base;
    const int w    = t >> 6;
    const int lane = t & 63;

    if (cnt <= CAP) {
        if (t < RPB) hist[t] = 0;
        __syncthreads();
        for (int i = base + t; i < end; i += 1024)
            atomicAdd(&hist[(((unsigned)staged[i].x) >> 16) & (RPB - 1)], 1);
        __syncthreads();
        const int v = (t < RPB) ? hist[t] : 0;
        for (int off = 1; off < RPB; off <<= 1) {
            int u = (t < RPB && t >= off) ? hist[t - off] : 0;
            __syncthreads();
            if (t < RPB) hist[t] += u;
            __syncthreads();
        }
        if (t < RPB) {
            rstart[t] = hist[t] - v;       // exclusive, bucket-relative
            cur[t]    = hist[t] - v;
        }
        if (t == 0) rstart[RPB] = cnt;
        __syncthreads();
        for (int i = base + t; i < end; i += 1024) {
            int2 e = staged[i];
            int r = (((unsigned)e.x) >> 16) & (RPB - 1);
            int p = atomicAdd(&cur[r], 1);
            eds[p] = make_int2(e.x & 0xFFFF, e.y);
        }
        __syncthreads();

        const float bv = bias[lane];
        #pragma unroll
        for (int rr = 0; rr < 8; ++rr) {
            const int row = w * 8 + rr;
            const int jb = rstart[row];
            const int je = rstart[row + 1];
            float a0 = 0.f, a1 = 0.f, a2 = 0.f, a3 = 0.f;
            float a4 = 0.f, a5 = 0.f, a6 = 0.f, a7 = 0.f;
            int j = jb;
            for (; j + 8 <= je; j += 8) {
                const int2 e0 = eds[j + 0];
                const int2 e1 = eds[j + 1];
                const int2 e2 = eds[j + 2];
                const int2 e3 = eds[j + 3];
                const int2 e4 = eds[j + 4];
                const int2 e5 = eds[j + 5];
                const int2 e6 = eds[j + 6];
                const int2 e7 = eds[j + 7];
                a0 += __int_as_float(e0.y) * bf2f(S16[(size_t)e0.x * NF + lane]);
                a1 += __int_as_float(e1.y) * bf2f(S16[(size_t)e1.x * NF + lane]);
                a2 += __int_as_float(e2.y) * bf2f(S16[(size_t)e2.x * NF + lane]);
                a3 += __int_as_float(e3.y) * bf2f(S16[(size_t)e3.x * NF + lane]);
                a4 += __int_as_float(e4.y) * bf2f(S16[(size_t)e4.x * NF + lane]);
                a5 += __int_as_float(e5.y) * bf2f(S16[(size_t)e5.x * NF + lane]);
                a6 += __int_as_float(e6.y) * bf2f(S16[(size_t)e6.x * NF + lane]);
                a7 += __int_as_float(e7.y) * bf2f(S16[(size_t)e7.x * NF + lane]);
            }
            for (; j + 2 <= je; j += 2) {
                const int2 e0 = eds[j + 0];
                const int2 e1 = eds[j + 1];
                a0 += __int_as_float(e0.y) * bf2f(S16[(size_t)e0.x * NF + lane]);
                a1 += __int_as_float(e1.y) * bf2f(S16[(size_t)e1.x * NF + lane]);
            }
            if (j < je) {
                const int2 e = eds[j];
                a0 += __int_as_float(e.y) * bf2f(S16[(size_t)e.x * NF + lane]);
            }
            const float acc = bv + (((a0 + a1) + (a2 + a3)) + ((a4 + a5) + (a6 + a7)));
            out[(size_t)(k * RPB + row) * NF + lane] = fmaxf(acc, 0.f);
        }
    } else {
        // overflow fallback: LDS fp32 accumulators (correct, slow, unused here)
        float* acc = (float*)eds;               // RPB*NF floats = 32 KB
        for (int i = t; i < RPB * NF; i += 1024) acc[i] = 0.f;
        __syncthreads();
        for (int j = base + w; j < end; j += 16) {
            int2 e = staged[j];
            int r = (((unsigned)e.x) >> 16) & (RPB - 1);
            float s = bf2f(S16[(size_t)(e.x & 0xFFFF) * NF + lane]);
            atomicAdd(&acc[r * NF + lane], __int_as_float(e.y) * s);
        }
        __syncthreads();
        for (int i = t; i < RPB * NF; i += 1024) {
            int f = i & (NF - 1);
            out[(size_t)k * RPB * NF + i] = fmaxf(acc[i] + bias[f], 0.f);
        }
    }
}

extern "C" void kernel_launch(void* const* d_in, const int* in_sizes, int n_in,
                              void* d_out, int out_size, void* d_ws, size_t ws_size,
                              hipStream_t stream)
{
    const float* X     = (const float*)d_in[0];
    const int*   erows = (const int*)  d_in[1];
    const int*   ecols = (const int*)  d_in[2];
    const float* evals = (const float*)d_in[3];
    const float* W     = (const float*)d_in[4];
    const float* bias  = (const float*)d_in[5];
    float*       out   = (float*)d_out;

    const int n_nodes = in_sizes[0] / NF;
    const int n_edges = in_sizes[1];
    int shift = 0; while ((NBKT << shift) < n_nodes) ++shift;   // 7

    // workspace layout
    char* ws = (char*)d_ws;
    unsigned short* S16 = (unsigned short*)(ws);                          // 8 MB
    int2* staged         = (int2*)(ws + (size_t)n_nodes * NF * 2);        // 8 MB
    int*  bucket_counts  = (int*)((char*)staged + (size_t)n_edges * 8);
    int*  bucketbase     = (int*)((char*)bucket_counts + (NBKT + 4) * 4);
    int*  bucket_cursor  = (int*)((char*)bucketbase    + (NBKT + 4) * 4);

    const int sblocks = (n_edges + CHUNK - 1) / CHUNK;   // 256

    hipMemsetAsync(bucket_counts, 0, (size_t)NBKT * 4, stream);
    gemm_bf16_hist<<<n_nodes / 64, 256, 0, stream>>>(X, W, S16, erows,
                                                     bucket_counts, n_edges, shift);
    scan_buckets  <<<1, NBKT, 0, stream>>>(bucket_counts, bucketbase,
                                           bucket_cursor, n_edges);
    bucket_scatter<<<sblocks, 512, 0, stream>>>(erows, ecols, evals, bucket_cursor,
                                                staged, n_edges, shift);
    bucket_gather <<<NBKT, 1024, 0, stream>>>(bucketbase, staged, S16, bias, out);
}